// Round 7
// baseline (135.874 us; speedup 1.0000x reference)
//
#include <hip/hip_runtime.h>
#include <cstdint>

#define PI_F 3.14159265358979323846f

typedef float v2f __attribute__((ext_vector_type(2)));

__device__ __forceinline__ float fract_(float x)  { return __builtin_amdgcn_fractf(x); }
__device__ __forceinline__ float sin2pi_(float r) { return __builtin_amdgcn_sinf(r); }  // sin(2*pi*r)
__device__ __forceinline__ float cos2pi_(float r) { return __builtin_amdgcn_cosf(r); }  // cos(2*pi*r)
__device__ __forceinline__ v2f  splat2(float x)   { v2f r; r.x = x; r.y = x; return r; }

// ---------------------------------------------------------------------------
// Cross-lane partners via compiler-generated DPP only (v_mov_b32_dpp):
// hazards are backend-managed, encodings are textbook. ctrl must be an
// integer-constant-expression AT THE BUILTIN CALL -> template parameter
// (round-6 failed compiling with a runtime function argument).
//   xor8: row_ror:8 (0x128). ror-8 within a 16-lane row == lane^8 (rotation
//         direction ambiguity vanishes at N=8: (i+8)%16 == (i-8)%16).
//   xor1: quad_perm [1,0,3,2] -> ctrl 0xB1.
//   xor2: quad_perm [2,3,0,1] -> ctrl 0x4E.
// ---------------------------------------------------------------------------
template <int CTRL>
__device__ __forceinline__ float dpp_mov(float x) {
    return __uint_as_float((uint32_t)__builtin_amdgcn_update_dpp(
        0, (int)__float_as_uint(x), CTRL, 0xF, 0xF, true));
}
__device__ __forceinline__ float xor8_dpp(float x) { return dpp_mov<0x128>(x); }
__device__ __forceinline__ float xor1_dpp(float x) { return dpp_mov<0xB1>(x); }
__device__ __forceinline__ float xor2_dpp(float x) { return dpp_mov<0x4E>(x); }

// ---------------------------------------------------------------------------
// Kernel A: ballot-based sign pack (verbatim round-2, proven ~10us, BW-bound).
// One WAVE per item; lane l loads float4 at row offset 4l -> contiguous
// 1KB/instr reads. Chain-major output layout:
//   word(cw,h) = pr[item*8 + cw*2 + h]
//   low  16 bits: bit j = sign z[item*256 + 64cw + 4j + 2h    ]
//   high 16 bits: bit j = sign z[item*256 + 64cw + 4j + 2h + 1]
// ---------------------------------------------------------------------------
extern "C" __global__ void __launch_bounds__(256)
pack_signs(const float4* __restrict__ zr4, const float4* __restrict__ zi4,
           uint32_t* __restrict__ pr, uint32_t* __restrict__ pim) {
    const int lane = threadIdx.x & 63;
    const int w    = threadIdx.x >> 6;
    const int item = blockIdx.x * 4 + w;

    const float4 fr = zr4[(size_t)item * 64 + lane];
    const float4 fi = zi4[(size_t)item * 64 + lane];

    const uint64_t Mr0 = __ballot(fr.x < 0.f);   // chain 0: k = 4l
    const uint64_t Mr1 = __ballot(fr.y < 0.f);   // chain 1: k = 4l+1
    const uint64_t Mr2 = __ballot(fr.z < 0.f);   // chain 2
    const uint64_t Mr3 = __ballot(fr.w < 0.f);   // chain 3
    const uint64_t Mi0 = __ballot(fi.x < 0.f);
    const uint64_t Mi1 = __ballot(fi.y < 0.f);
    const uint64_t Mi2 = __ballot(fi.z < 0.f);
    const uint64_t Mi3 = __ballot(fi.w < 0.f);

    if (lane < 16) {
        const int comp = lane >> 3;              // 0: re, 1: im
        const int sub  = lane & 7;               // word index 0..7
        const int cw   = sub >> 1;               // chunk
        const int h    = sub & 1;                // chain-pair half
        const uint64_t ma = comp ? (h ? Mi2 : Mi0) : (h ? Mr2 : Mr0);
        const uint64_t mb = comp ? (h ? Mi3 : Mi1) : (h ? Mr3 : Mr1);
        const int sh = 16 * cw;
        const uint32_t word = ((uint32_t)(ma >> sh) & 0xFFFFu)
                            | (((uint32_t)(mb >> sh) & 0xFFFFu) << 16);
        uint32_t* dst = comp ? pim : pr;
        dst[(size_t)item * 8 + sub] = word;
    }
}

// ---------------------------------------------------------------------------
// Kernel B: refiner. FP trajectory bit-identical to the 36.0-absmax baseline.
// Round-7 == round-6 with the DPP ctrl as template arg (compile fix only):
// round-4's h-split (lowest measured VALU-busy, 26.6us) with ALL cross-lane
// ops as compiler-generated DPP. Lane layout remapped so every fold stride
// is DPP-reachable:
//   bit0,1 = cw (chunk), bit2 = il0, bit3 = h (chain pair), bit4,5 = il1,2.
// Per t: T-exchange = xor8; reduce = xor8 (h fold), xor1 (cw0), xor2 (cw1).
// Fold values/order match baseline ((A0+A1)+(A2+A3)), ((S0+S1)+(S2+S3));
// off-lane variants are single-add commutations -> bit-exact on every lane.
// ---------------------------------------------------------------------------
extern "C" __global__ void __launch_bounds__(256)
refine(const float* __restrict__ th0, const float* __restrict__ r0,
       const float* __restrict__ a_th_raw, const float* __restrict__ a_r_raw,
       const float* __restrict__ l_th_raw, const float* __restrict__ l_r_raw,
       const uint32_t* __restrict__ pr, const uint32_t* __restrict__ pim,
       float* __restrict__ out) {
    const int lane = threadIdx.x & 63;
    const int w    = threadIdx.x >> 6;       // wave id 0..3: owns 8 items
    const int cw   = lane & 3;               // k-chunk: k in [cw*64, cw*64+64)
    const int h    = (lane >> 3) & 1;        // chain pair (2h, 2h+1); owns u_h
    const int il   = ((lane >> 2) & 1) | (((lane >> 4) & 3) << 1);
    const int sub  = (cw << 1) | h;          // sign-word index (layout of pack)
    const int item = blockIdx.x * 32 + w * 8 + il;

    __shared__ float sp[4][10];              // ath, ar, lth, lr per step

    if (threadIdx.x < 40) {
        const int a = threadIdx.x / 10, i = threadIdx.x % 10;
        const float* src = (a == 0) ? a_th_raw : (a == 1) ? a_r_raw
                         : (a == 2) ? l_th_raw : l_r_raw;
        const float v  = log1pf(expf(src[i]));           // verbatim round-1 expr
        const float hi = (a < 2) ? 0.2f : 1.0f;
        sp[a][i] = fminf(fmaxf(v, 1e-6f), hi);
    }

    // this thread's sign words (chain-major layout from pack_signs)
    const uint32_t br = pr [(size_t)item * 8 + sub];
    const uint32_t bi = pim[(size_t)item * 8 + sub];

    // u_own: h=0 -> atanh(clip(theta/60)); h=1 -> atanh(2*clip(r/2000)-1).
    // Per-component expressions verbatim; one atanhf on the selected arg.
    float y = th0[item] * (1.0f / 60.0f);
    y = fminf(fmaxf(y, -1.0f + 1e-6f), 1.0f - 1e-6f);
    float sR = r0[item] * (1.0f / 2000.0f);
    sR = fminf(fmaxf(sR, 1e-6f), 1.0f - 1e-6f);
    const float yR = 2.0f * sR - 1.0f;
    float u_own = atanhf(h ? yR : y);

    // chain-pair k seeds: exact small ints, identical values to baseline
    const float k0a = (float)(cw * 64 + 2 * h);
    const float k0b = (float)(cw * 64 + 2 * h + 1);

    __syncthreads();                          // sp[] ready (only barrier)

    for (int t = 0; t < 10; ++t) {
        // one tanh per lane; exchange via DPP xor8 (h-partner, bit-copy)
        const float T_own = tanhf(u_own);
        const float T_oth = xor8_dpp(T_own);
        const float T0 = h ? T_oth : T_own;
        const float T1 = h ? T_own : T_oth;

        const float th_rad = (PI_F / 3.0f) * T0;          // 60*T0 deg -> rad
        const float sth = sinf(th_rad), cth = cosf(th_rad);
        const float r   = 1000.0f * (T1 + 1.0f);
        const float crev = 0.5f * sth - 2e-4f * r;        // revolutions per unit k

        // rotation step e^{i*2pi*4*crev}
        const float d4 = fract_(4.0f * crev);
        const v2f C4 = splat2(cos2pi_(d4));
        const v2f S4 = splat2(sin2pi_(d4));

        // seed the single chain pair (chains 2h, 2h+1 of chunk cw)
        const float rva = fract_(k0a * crev);
        const float rvb = fract_(k0b * crev);
        v2f c, s, kf, acc;
        c.x  = cos2pi_(rva);  c.y  = cos2pi_(rvb);
        s.x  = sin2pi_(rva);  s.y  = sin2pi_(rvb);
        kf.x = k0a;           kf.y = k0b;
        acc  = splat2(0.0f);

        const v2f mtwo = splat2(-2.0f);
        const v2f one  = splat2(1.0f);
        const v2f cub  = splat2(-(1.0f / 196608.0f));
        const v2f four = splat2(4.0f);

        #pragma unroll
        for (int j = 0; j < 16; ++j) {
            // chain A bit = j, chain B bit = 16+j  (compile-time shifts)
            const uint32_t mreA = (br << (31 - j)) & 0x80000000u;
            const uint32_t mreB = (br << (15 - j)) & 0x80000000u;
            const uint32_t mimA = (bi << (31 - j)) & 0x80000000u;
            const uint32_t mimB = (bi << (15 - j)) & 0x80000000u;
            const v2f cs = c, ss = s;
            v2f zc, zs;                                 // z_im*cos, z_re*sin
            zc.x = __uint_as_float(__float_as_uint(cs.x) ^ mimA);
            zc.y = __uint_as_float(__float_as_uint(cs.y) ^ mimB);
            zs.x = __uint_as_float(__float_as_uint(ss.x) ^ mreA);
            zs.y = __uint_as_float(__float_as_uint(ss.y) ^ mreB);
            const v2f w0 = zc - zs;
            // cubic sigma term: -sin(4phi)/786432 = -s*c*(1-2s^2)/196608
            const v2f u2 = ss * ss;
            const v2f t2 = __builtin_elementwise_fma(mtwo, u2, one);
            const v2f sc = ss * cs;
            const v2f v  = sc * t2;
            const v2f W  = __builtin_elementwise_fma(v, cub, w0 * 0.0625f);
            acc = __builtin_elementwise_fma(kf, W, acc);
            kf  = kf + four;
            // rotate phase by 4*crev revolutions
            const v2f tA = ss * S4;
            const v2f tB = cs * S4;
            c = __builtin_elementwise_fma(cs, C4, -tA);
            s = __builtin_elementwise_fma(ss, C4, tB);
        }
        // within-pair fold: A_{2h} + A_{2h+1}
        float S = acc.x + acc.y;
        // h fold (xor8): -> (A0+A1)+(A2+A3) per chunk (commutation-exact)
        S += xor8_dpp(S);
        // cw folds (xor1 then xor2): -> (S0+S1)+(S2+S3) (commutation-exact)
        S += xor1_dpp(S);
        S += xor2_dpp(S);

        // tail, own component only. Associations verbatim:
        //   g0 = ((-(pi^2/3) * cth) * (1-T0^2)) * S
        //   g1 = ((0.4*pi) * (1-T1^2)) * S      (0.4f*PI_F folded at compile time)
        const float Ccth = -(PI_F * PI_F / 3.0f) * cth;
        const float coef = h ? (0.4f * PI_F) : Ccth;
        const float Tf   = 1.0f - T_own * T_own;
        const float g    = coef * Tf * S;
        const float alp  = sp[h][t];          // ath / ar
        const float lam  = sp[2 + h][t];      // lth / lr
        const float den  = fmaxf(fabsf(g), 1e-6f) + lam;
        float st = alp * g / den;
        st = fminf(fmaxf(st, -0.1f), 0.1f);
        u_own -= st;
    }

    // epilogue: one tanh; h=0 writes theta, h=1 writes r (chunk 0 only)
    const float tv  = tanhf(u_own);
    const float val = h ? 1000.0f * (tv + 1.0f) : 60.0f * tv;
    if (cw == 0) {
        out[2 * item + h] = val;
    }
}

extern "C" void kernel_launch(void* const* d_in, const int* in_sizes, int n_in,
                              void* d_out, int out_size, void* d_ws, size_t ws_size,
                              hipStream_t stream) {
    const float* zr   = (const float*)d_in[0];
    const float* zi   = (const float*)d_in[1];
    const float* th0  = (const float*)d_in[2];
    const float* r0   = (const float*)d_in[3];
    const float* athr = (const float*)d_in[4];
    const float* arr  = (const float*)d_in[5];
    const float* lthr = (const float*)d_in[6];
    const float* lrr  = (const float*)d_in[7];

    const int B = in_sizes[2];          // 32768

    uint32_t* pr  = (uint32_t*)d_ws;     // B*8 words = 1 MB
    uint32_t* pim = pr + (size_t)B * 8;  // B*8 words = 1 MB

    pack_signs<<<B / 4, 256, 0, stream>>>((const float4*)zr, (const float4*)zi,
                                          pr, pim);
    refine<<<B / 32, 256, 0, stream>>>(th0, r0, athr, arr, lthr, lrr,
                                       pr, pim, (float*)d_out);
}